// Round 2
// baseline (3135.452 us; speedup 1.0000x reference)
//
#include <hip/hip_runtime.h>
#include <hip/hip_cooperative_groups.h>

namespace cg = cooperative_groups;

#define E 1024
#define H 4096
#define NLAYER 24
#define V 50277
#define NB 256
#define NT 1024
#define NWAVE ((NB * NT) / 64)   // 4096 waves
#define LN_EPS 1e-5f

struct Params {
  const float* emb;   const float* ln0_w; const float* ln0_b;
  const float* ln1_w; const float* ln1_b;
  const float* tmk;   const float* tmv;   const float* tmr;
  const float* tf;    const float* td;
  const float* kw;    const float* vw;    const float* rw;  const float* ow;
  const float* ln2_w; const float* ln2_b;
  const float* ftmk;  const float* ftmr;
  const float* fkw;   const float* fvw;   const float* frw;
  const float* lnow;  const float* lnob;  const float* headw;
  const float* st;    const int* tok;
  float* out; float* ws;
};

__device__ __forceinline__ float warp_sum(float v) {
#pragma unroll
  for (int off = 32; off; off >>= 1) v += __shfl_down(v, off);
  return v;
}

// full-block (1024-thread) sum; red is 16-entry LDS scratch
__device__ float block_sum(float v, float* red) {
  v = warp_sum(v);
  const int wid = threadIdx.x >> 6, lane = threadIdx.x & 63;
  if (lane == 0) red[wid] = v;
  __syncthreads();
  float s = (threadIdx.x < 16) ? red[threadIdx.x] : 0.f;
  if (wid == 0) {
#pragma unroll
    for (int off = 8; off; off >>= 1) s += __shfl_down(s, off);
    if (lane == 0) red[0] = s;
  }
  __syncthreads();
  float r = red[0];
  __syncthreads();
  return r;
}

// K=1024 dot: wave-wide, lane reads 4x float4; result valid in lane 0
__device__ __forceinline__ float dot1024(const float* __restrict__ Wrow,
                                         const float* vec, int lane) {
  const float4* W4 = (const float4*)Wrow;
  const float4* v4 = (const float4*)vec;
  float acc = 0.f;
#pragma unroll
  for (int p = 0; p < 4; ++p) {
    float4 w = W4[lane + p * 64];
    float4 x = v4[lane + p * 64];
    acc += w.x * x.x + w.y * x.y + w.z * x.z + w.w * x.w;
  }
  return warp_sum(acc);
}

__global__ __launch_bounds__(NT, 1) void rwkv_kernel(Params p) {
  cg::grid_group grid = cg::this_grid();
  const int tid = threadIdx.x, bid = blockIdx.x;
  const int lane = tid & 63, wid = tid >> 6;
  const int gw = bid * (NT / 64) + wid;   // global wave id, 0..4095

  __shared__ __align__(16) float s_x[E];
  __shared__ __align__(16) float s_xk[E];
  __shared__ __align__(16) float s_xv[E];
  __shared__ __align__(16) float s_xr[E];
  __shared__ __align__(16) float s_wkv[E];
  __shared__ __align__(16) float s_sx[E];
  __shared__ __align__(16) float s_fxk[E];
  __shared__ __align__(16) float s_fxr[E];
  __shared__ __align__(16) float s_fk[H];
  __shared__ float s_red[16];
  __shared__ float s_part[16];

  float* ws_x  = p.ws;
  float* ws_k  = p.ws + E;
  float* ws_v  = p.ws + 2 * E;
  float* ws_r  = p.ws + 3 * E;
  float* ws_sx = p.ws + 4 * E;
  float* ws_fr = p.ws + 5 * E;
  float* ws_fk = p.ws + 6 * E;          // H floats

  float* out_st = p.out + V;

  const int token = p.tok[0];

  // x = LN0(emb[token]) -- redundant per block, lives in s_x
  {
    float v = p.emb[(size_t)token * E + tid];
    float m = block_sum(v, s_red) * (1.f / E);
    float d = v - m;
    float var = block_sum(d * d, s_red) * (1.f / E);
    s_x[tid] = d / sqrtf(var + LN_EPS) * p.ln0_w[tid] + p.ln0_b[tid];
  }
  __syncthreads();

  for (int l = 0; l < NLAYER; ++l) {
    const float* stl = p.st + (size_t)5 * l * E;   // [ffn_x, att_x, aa, bb, pp]
    float* ostl = out_st + (size_t)5 * l * E;

    // ---------------- Phase A: LN1, mixing, k/v/r matvecs ----------------
    {
      float xv_ = s_x[tid];
      float m = block_sum(xv_, s_red) * (1.f / E);
      float d = xv_ - m;
      float var = block_sum(d * d, s_red) * (1.f / E);
      float xn = d / sqrtf(var + LN_EPS) * p.ln1_w[l * E + tid] + p.ln1_b[l * E + tid];
      float ax = stl[1 * E + tid];
      float tk = p.tmk[l * E + tid], tv = p.tmv[l * E + tid], tr = p.tmr[l * E + tid];
      s_xk[tid] = xn * tk + ax * (1.f - tk);
      s_xv[tid] = xn * tv + ax * (1.f - tv);
      s_xr[tid] = xn * tr + ax * (1.f - tr);
      if (bid == 0) ostl[1 * E + tid] = xn;       // new att_x
    }
    __syncthreads();
    {
      int row = gw;                                // 3072 rows over 4096 waves
      if (row < 3 * E) {
        int mat = row >> 10, rm = row & (E - 1);
        const float* W; const float* vec;
        if (mat == 0)      { W = p.kw + (size_t)l * E * E; vec = s_xk; }
        else if (mat == 1) { W = p.vw + (size_t)l * E * E; vec = s_xv; }
        else               { W = p.rw + (size_t)l * E * E; vec = s_xr; }
        float dres = dot1024(W + (size_t)rm * E, vec, lane);
        if (lane == 0) {
          if (mat == 0)      ws_k[rm] = dres;
          else if (mat == 1) ws_v[rm] = dres;
          else               ws_r[rm] = 1.f / (1.f + expf(-dres));
        }
      }
    }
    grid.sync();

    // ---------------- Phase B: WKV elementwise + ow matvec ----------------
    {
      float kk = ws_k[tid], vv = ws_v[tid], rr = ws_r[tid];
      float ppv = stl[4 * E + tid], aav = stl[2 * E + tid], bbv = stl[3 * E + tid];
      float tfv = p.tf[l * E + tid], tdv = p.td[l * E + tid];
      float wwv = tfv + kk;
      float pm = fmaxf(ppv, wwv);
      float e1 = expf(ppv - pm), e2 = expf(wwv - pm);
      float a = e1 * aav + e2 * vv, b = e1 * bbv + e2;
      s_wkv[tid] = rr * a / b;
      float ww2 = ppv + tdv;
      float p2 = fmaxf(ww2, kk);
      float f1 = expf(ww2 - p2), f2 = expf(kk - p2);
      if (bid == 0) {
        ostl[2 * E + tid] = f1 * aav + f2 * vv;    // naa
        ostl[3 * E + tid] = f1 * bbv + f2;         // nbb
        ostl[4 * E + tid] = p2;                    // npp
      }
    }
    __syncthreads();
    {
      // 4 rows/block, 4 waves/row, K-chunks of 256
      int rloc = wid >> 2, kc = wid & 3;
      int row = bid * 4 + rloc;
      const float* Wrow = p.ow + (size_t)l * E * E + (size_t)row * E + kc * 256;
      const float4* W4 = (const float4*)Wrow;
      const float4* v4 = (const float4*)(s_wkv + kc * 256);
      float4 w = W4[lane]; float4 x = v4[lane];
      float acc = warp_sum(w.x * x.x + w.y * x.y + w.z * x.z + w.w * x.w);
      if (lane == 0) s_part[wid] = acc;
      __syncthreads();
      if (tid < 4) {
        int r2 = bid * 4 + tid;
        float dsum = s_part[tid * 4] + s_part[tid * 4 + 1] +
                     s_part[tid * 4 + 2] + s_part[tid * 4 + 3];
        ws_sx[r2] = s_x[r2] + dsum;
      }
    }
    grid.sync();

    // ---------------- Phase C: LN2, mixing, ffn_kw/frw matvecs ----------------
    {
      float sxv = ws_sx[tid];
      s_sx[tid] = sxv;
      float m = block_sum(sxv, s_red) * (1.f / E);
      float d = sxv - m;
      float var = block_sum(d * d, s_red) * (1.f / E);
      float xn2 = d / sqrtf(var + LN_EPS) * p.ln2_w[l * E + tid] + p.ln2_b[l * E + tid];
      float fx = stl[0 * E + tid];
      float ftk = p.ftmk[l * E + tid], ftr = p.ftmr[l * E + tid];
      s_fxk[tid] = xn2 * ftk + fx * (1.f - ftk);
      s_fxr[tid] = xn2 * ftr + fx * (1.f - ftr);
      if (bid == 0) ostl[0 * E + tid] = xn2;       // new ffn_x
    }
    __syncthreads();
    {
      for (int row = gw; row < H + E; row += NWAVE) {   // 5120 rows
        if (row < H) {
          const float* Wr = p.fkw + (size_t)l * H * E + (size_t)row * E;
          float dres = dot1024(Wr, s_fxk, lane);
          if (lane == 0) { float t = fmaxf(dres, 0.f); ws_fk[row] = t * t; }
        } else {
          int rr2 = row - H;
          const float* Wr = p.frw + (size_t)l * E * E + (size_t)rr2 * E;
          float dres = dot1024(Wr, s_fxr, lane);
          if (lane == 0) ws_fr[rr2] = 1.f / (1.f + expf(-dres));
        }
      }
    }
    grid.sync();

    // ---------------- Phase D: fvw matvec (K=4096), residual ----------------
    {
#pragma unroll
      for (int i = 0; i < 4; ++i) s_fk[tid + i * NT] = ws_fk[tid + i * NT];
      __syncthreads();
      int rloc = wid >> 2, kc = wid & 3;               // kc: 1024-wide chunk
      int row = bid * 4 + rloc;
      const float* Wrow = p.fvw + (size_t)l * E * H + (size_t)row * H + kc * 1024;
      const float4* W4 = (const float4*)Wrow;
      const float4* v4 = (const float4*)(s_fk + kc * 1024);
      float acc = 0.f;
#pragma unroll
      for (int pc = 0; pc < 4; ++pc) {
        float4 w = W4[lane + pc * 64];
        float4 x = v4[lane + pc * 64];
        acc += w.x * x.x + w.y * x.y + w.z * x.z + w.w * x.w;
      }
      acc = warp_sum(acc);
      if (lane == 0) s_part[wid] = acc;
      __syncthreads();
      if (tid < 4) {
        int r2 = bid * 4 + tid;
        float dsum = s_part[tid * 4] + s_part[tid * 4 + 1] +
                     s_part[tid * 4 + 2] + s_part[tid * 4 + 3];
        ws_x[r2] = s_sx[r2] + ws_fr[r2] * dsum;
      }
    }
    grid.sync();

    // reload x for next layer
    s_x[tid] = ws_x[tid];
    __syncthreads();
  }

  // ---------------- Head: LN_out + V x E matvec ----------------
  {
    float xv_ = s_x[tid];
    float m = block_sum(xv_, s_red) * (1.f / E);
    float d = xv_ - m;
    float var = block_sum(d * d, s_red) * (1.f / E);
    s_xk[tid] = d / sqrtf(var + LN_EPS) * p.lnow[tid] + p.lnob[tid];
  }
  __syncthreads();
  for (int row = gw; row < V; row += NWAVE) {
    const float* Wr = p.headw + (size_t)row * E;
    float dres = dot1024(Wr, s_xk, lane);
    if (lane == 0) p.out[row] = dres;
  }
}

extern "C" void kernel_launch(void* const* d_in, const int* in_sizes, int n_in,
                              void* d_out, int out_size, void* d_ws, size_t ws_size,
                              hipStream_t stream) {
  Params p;
  p.emb   = (const float*)d_in[0];
  p.ln0_w = (const float*)d_in[1];
  p.ln0_b = (const float*)d_in[2];
  p.ln1_w = (const float*)d_in[3];
  p.ln1_b = (const float*)d_in[4];
  p.tmk   = (const float*)d_in[5];
  p.tmv   = (const float*)d_in[6];
  p.tmr   = (const float*)d_in[7];
  p.tf    = (const float*)d_in[8];
  p.td    = (const float*)d_in[9];
  p.kw    = (const float*)d_in[10];
  p.vw    = (const float*)d_in[11];
  p.rw    = (const float*)d_in[12];
  p.ow    = (const float*)d_in[13];
  p.ln2_w = (const float*)d_in[14];
  p.ln2_b = (const float*)d_in[15];
  p.ftmk  = (const float*)d_in[16];
  p.ftmr  = (const float*)d_in[17];
  p.fkw   = (const float*)d_in[18];
  p.fvw   = (const float*)d_in[19];
  p.frw   = (const float*)d_in[20];
  p.lnow  = (const float*)d_in[21];
  p.lnob  = (const float*)d_in[22];
  p.headw = (const float*)d_in[23];
  // setup_inputs() dict order: "token" is entry 24 (scalar, size 1),
  // "state" appended after the literal as entry 25. Defensive: detect by size.
  if (in_sizes[24] == 1) {
    p.tok = (const int*)d_in[24];
    p.st  = (const float*)d_in[25];
  } else {
    p.st  = (const float*)d_in[24];
    p.tok = (const int*)d_in[25];
  }
  p.out   = (float*)d_out;
  p.ws    = (float*)d_ws;

  void* args[] = { &p };
  hipLaunchCooperativeKernel((const void*)rwkv_kernel, dim3(NB), dim3(NT),
                             args, 0, stream);
}

// Round 3
// 1779.535 us; speedup vs baseline: 1.7620x; 1.7620x over previous
//
#include <hip/hip_runtime.h>

#define E 1024
#define H 4096
#define NLAYER 24
#define V 50277
#define NB 256
#define NT 1024
#define NWAVE ((NB * NT) / 64)   // 4096 waves
#define LN_EPS 1e-5f

struct Params {
  const float* emb;   const float* ln0_w; const float* ln0_b;
  const float* ln1_w; const float* ln1_b;
  const float* tmk;   const float* tmv;   const float* tmr;
  const float* tf;    const float* td;
  const float* kw;    const float* vw;    const float* rw;  const float* ow;
  const float* ln2_w; const float* ln2_b;
  const float* ftmk;  const float* ftmr;
  const float* fkw;   const float* fvw;   const float* frw;
  const float* lnow;  const float* lnob;  const float* headw;
  const float* st;    const int* tok;
  float* out; float* ws;
};

// ---- agent-scope (device-coherent, L2-bypassing) load/store helpers ----
__device__ __forceinline__ void stg(float* p, float v) {
  __hip_atomic_store(p, v, __ATOMIC_RELAXED, __HIP_MEMORY_SCOPE_AGENT);
}
__device__ __forceinline__ float ldg1(const float* p) {
  return __hip_atomic_load(p, __ATOMIC_RELAXED, __HIP_MEMORY_SCOPE_AGENT);
}

// ---- lightweight grid barrier: single counter, thread-0 spin ----
// cnt is zeroed by hipMemsetAsync before every kernel launch (graph node).
__device__ __forceinline__ void gbar(unsigned* cnt, unsigned target) {
  __syncthreads();
  if (threadIdx.x == 0) {
    __hip_atomic_fetch_add(cnt, 1u, __ATOMIC_RELEASE, __HIP_MEMORY_SCOPE_AGENT);
    while (__hip_atomic_load(cnt, __ATOMIC_ACQUIRE, __HIP_MEMORY_SCOPE_AGENT) < target)
      __builtin_amdgcn_s_sleep(2);
  }
  __syncthreads();
}

__device__ __forceinline__ float warp_sum(float v) {
#pragma unroll
  for (int off = 32; off; off >>= 1) v += __shfl_down(v, off);
  return v;
}

// full-block (1024-thread) sum; red is 16-entry LDS scratch
__device__ float block_sum(float v, float* red) {
  v = warp_sum(v);
  const int wid = threadIdx.x >> 6, lane = threadIdx.x & 63;
  if (lane == 0) red[wid] = v;
  __syncthreads();
  float s = (threadIdx.x < 16) ? red[threadIdx.x] : 0.f;
  if (wid == 0) {
#pragma unroll
    for (int off = 8; off; off >>= 1) s += __shfl_down(s, off);
    if (lane == 0) red[0] = s;
  }
  __syncthreads();
  float r = red[0];
  __syncthreads();
  return r;
}

// K=1024 dot: wave-wide, lane reads 4x float4; result valid in lane 0
__device__ __forceinline__ float dot1024(const float* __restrict__ Wrow,
                                         const float* vec, int lane) {
  const float4* W4 = (const float4*)Wrow;
  const float4* v4 = (const float4*)vec;
  float acc = 0.f;
#pragma unroll
  for (int p = 0; p < 4; ++p) {
    float4 w = W4[lane + p * 64];
    float4 x = v4[lane + p * 64];
    acc += w.x * x.x + w.y * x.y + w.z * x.z + w.w * x.w;
  }
  return warp_sum(acc);
}

__global__ __launch_bounds__(NT, 1) void rwkv_kernel(Params p) {
  const int tid = threadIdx.x, bid = blockIdx.x;
  const int lane = tid & 63, wid = tid >> 6;
  const int gw = bid * (NT / 64) + wid;   // global wave id, 0..4095

  __shared__ __align__(16) float s_x[E];
  __shared__ __align__(16) float s_xk[E];
  __shared__ __align__(16) float s_xv[E];
  __shared__ __align__(16) float s_xr[E];
  __shared__ __align__(16) float s_wkv[E];
  __shared__ __align__(16) float s_sx[E];
  __shared__ __align__(16) float s_fxk[E];
  __shared__ __align__(16) float s_fxr[E];
  __shared__ __align__(16) float s_fk[H];
  __shared__ float s_red[16];
  __shared__ float s_part[16];

  // ws layout: [0..1024) control; data after
  unsigned* bar_cnt = (unsigned*)p.ws;
  float* wsd  = p.ws + 1024;
  float* ws_x  = wsd;
  float* ws_k  = wsd + E;
  float* ws_v  = wsd + 2 * E;
  float* ws_r  = wsd + 3 * E;
  float* ws_sx = wsd + 4 * E;
  float* ws_fr = wsd + 5 * E;
  float* ws_fk = wsd + 6 * E;          // H floats

  unsigned gen = 0;

  float* out_st = p.out + V;

  const int token = p.tok[0];

  // x = LN0(emb[token]) -- redundant per block, lives in s_x
  {
    float v = p.emb[(size_t)token * E + tid];
    float m = block_sum(v, s_red) * (1.f / E);
    float d = v - m;
    float var = block_sum(d * d, s_red) * (1.f / E);
    s_x[tid] = d / sqrtf(var + LN_EPS) * p.ln0_w[tid] + p.ln0_b[tid];
  }
  __syncthreads();

  for (int l = 0; l < NLAYER; ++l) {
    const float* stl = p.st + (size_t)5 * l * E;   // [ffn_x, att_x, aa, bb, pp]
    float* ostl = out_st + (size_t)5 * l * E;

    // ---------------- Phase A: LN1, mixing, k/v/r matvecs ----------------
    {
      float xv_ = s_x[tid];
      float m = block_sum(xv_, s_red) * (1.f / E);
      float d = xv_ - m;
      float var = block_sum(d * d, s_red) * (1.f / E);
      float xn = d / sqrtf(var + LN_EPS) * p.ln1_w[l * E + tid] + p.ln1_b[l * E + tid];
      float ax = stl[1 * E + tid];
      float tk = p.tmk[l * E + tid], tv = p.tmv[l * E + tid], tr = p.tmr[l * E + tid];
      s_xk[tid] = xn * tk + ax * (1.f - tk);
      s_xv[tid] = xn * tv + ax * (1.f - tv);
      s_xr[tid] = xn * tr + ax * (1.f - tr);
      if (bid == 0) ostl[1 * E + tid] = xn;       // new att_x
    }
    __syncthreads();
    {
      int row = gw;                                // 3072 rows over 4096 waves
      if (row < 3 * E) {
        int mat = row >> 10, rm = row & (E - 1);
        const float* W; const float* vec;
        if (mat == 0)      { W = p.kw + (size_t)l * E * E; vec = s_xk; }
        else if (mat == 1) { W = p.vw + (size_t)l * E * E; vec = s_xv; }
        else               { W = p.rw + (size_t)l * E * E; vec = s_xr; }
        float dres = dot1024(W + (size_t)rm * E, vec, lane);
        if (lane == 0) {
          if (mat == 0)      stg(&ws_k[rm], dres);
          else if (mat == 1) stg(&ws_v[rm], dres);
          else               stg(&ws_r[rm], 1.f / (1.f + expf(-dres)));
        }
      }
    }
    gbar(bar_cnt, ++gen * NB);

    // ---------------- Phase B: WKV elementwise + ow matvec ----------------
    {
      float kk = ldg1(&ws_k[tid]), vv = ldg1(&ws_v[tid]), rr = ldg1(&ws_r[tid]);
      float ppv = stl[4 * E + tid], aav = stl[2 * E + tid], bbv = stl[3 * E + tid];
      float tfv = p.tf[l * E + tid], tdv = p.td[l * E + tid];
      float wwv = tfv + kk;
      float pm = fmaxf(ppv, wwv);
      float e1 = expf(ppv - pm), e2 = expf(wwv - pm);
      float a = e1 * aav + e2 * vv, b = e1 * bbv + e2;
      s_wkv[tid] = rr * a / b;
      float ww2 = ppv + tdv;
      float p2 = fmaxf(ww2, kk);
      float f1 = expf(ww2 - p2), f2 = expf(kk - p2);
      if (bid == 0) {
        ostl[2 * E + tid] = f1 * aav + f2 * vv;    // naa
        ostl[3 * E + tid] = f1 * bbv + f2;         // nbb
        ostl[4 * E + tid] = p2;                    // npp
      }
    }
    __syncthreads();
    {
      // 4 rows/block, 4 waves/row, K-chunks of 256
      int rloc = wid >> 2, kc = wid & 3;
      int row = bid * 4 + rloc;
      const float* Wrow = p.ow + (size_t)l * E * E + (size_t)row * E + kc * 256;
      const float4* W4 = (const float4*)Wrow;
      const float4* v4 = (const float4*)(s_wkv + kc * 256);
      float4 w = W4[lane]; float4 x = v4[lane];
      float acc = warp_sum(w.x * x.x + w.y * x.y + w.z * x.z + w.w * x.w);
      if (lane == 0) s_part[wid] = acc;
      __syncthreads();
      if (tid < 4) {
        int r2 = bid * 4 + tid;
        float dsum = s_part[tid * 4] + s_part[tid * 4 + 1] +
                     s_part[tid * 4 + 2] + s_part[tid * 4 + 3];
        stg(&ws_sx[r2], s_x[r2] + dsum);
      }
    }
    gbar(bar_cnt, ++gen * NB);

    // ---------------- Phase C: LN2, mixing, ffn_kw/frw matvecs ----------------
    {
      float sxv = ldg1(&ws_sx[tid]);
      s_sx[tid] = sxv;
      float m = block_sum(sxv, s_red) * (1.f / E);
      float d = sxv - m;
      float var = block_sum(d * d, s_red) * (1.f / E);
      float xn2 = d / sqrtf(var + LN_EPS) * p.ln2_w[l * E + tid] + p.ln2_b[l * E + tid];
      float fx = stl[0 * E + tid];
      float ftk = p.ftmk[l * E + tid], ftr = p.ftmr[l * E + tid];
      s_fxk[tid] = xn2 * ftk + fx * (1.f - ftk);
      s_fxr[tid] = xn2 * ftr + fx * (1.f - ftr);
      if (bid == 0) ostl[0 * E + tid] = xn2;       // new ffn_x
    }
    __syncthreads();
    {
      for (int row = gw; row < H + E; row += NWAVE) {   // 5120 rows
        if (row < H) {
          const float* Wr = p.fkw + (size_t)l * H * E + (size_t)row * E;
          float dres = dot1024(Wr, s_fxk, lane);
          if (lane == 0) { float t = fmaxf(dres, 0.f); stg(&ws_fk[row], t * t); }
        } else {
          int rr2 = row - H;
          const float* Wr = p.frw + (size_t)l * E * E + (size_t)rr2 * E;
          float dres = dot1024(Wr, s_fxr, lane);
          if (lane == 0) stg(&ws_fr[rr2], 1.f / (1.f + expf(-dres)));
        }
      }
    }
    gbar(bar_cnt, ++gen * NB);

    // ---------------- Phase D: fvw matvec (K=4096), residual ----------------
    {
#pragma unroll
      for (int i = 0; i < 4; ++i) s_fk[tid + i * NT] = ldg1(&ws_fk[tid + i * NT]);
      __syncthreads();
      int rloc = wid >> 2, kc = wid & 3;               // kc: 1024-wide chunk
      int row = bid * 4 + rloc;
      const float* Wrow = p.fvw + (size_t)l * E * H + (size_t)row * H + kc * 1024;
      const float4* W4 = (const float4*)Wrow;
      const float4* v4 = (const float4*)(s_fk + kc * 1024);
      float acc = 0.f;
#pragma unroll
      for (int pc = 0; pc < 4; ++pc) {
        float4 w = W4[lane + pc * 64];
        float4 x = v4[lane + pc * 64];
        acc += w.x * x.x + w.y * x.y + w.z * x.z + w.w * x.w;
      }
      acc = warp_sum(acc);
      if (lane == 0) s_part[wid] = acc;
      __syncthreads();
      if (tid < 4) {
        int r2 = bid * 4 + tid;
        float dsum = s_part[tid * 4] + s_part[tid * 4 + 1] +
                     s_part[tid * 4 + 2] + s_part[tid * 4 + 3];
        stg(&ws_x[r2], s_sx[r2] + ldg1(&ws_fr[r2]) * dsum);
      }
    }
    gbar(bar_cnt, ++gen * NB);

    // reload x for next layer
    s_x[tid] = ldg1(&ws_x[tid]);
    __syncthreads();
  }

  // ---------------- Head: LN_out + V x E matvec ----------------
  {
    float xv_ = s_x[tid];
    float m = block_sum(xv_, s_red) * (1.f / E);
    float d = xv_ - m;
    float var = block_sum(d * d, s_red) * (1.f / E);
    s_xk[tid] = d / sqrtf(var + LN_EPS) * p.lnow[tid] + p.lnob[tid];
  }
  __syncthreads();
  for (int row = gw; row < V; row += NWAVE) {
    const float* Wr = p.headw + (size_t)row * E;
    float dres = dot1024(Wr, s_xk, lane);
    if (lane == 0) p.out[row] = dres;
  }
}

extern "C" void kernel_launch(void* const* d_in, const int* in_sizes, int n_in,
                              void* d_out, int out_size, void* d_ws, size_t ws_size,
                              hipStream_t stream) {
  Params p;
  p.emb   = (const float*)d_in[0];
  p.ln0_w = (const float*)d_in[1];
  p.ln0_b = (const float*)d_in[2];
  p.ln1_w = (const float*)d_in[3];
  p.ln1_b = (const float*)d_in[4];
  p.tmk   = (const float*)d_in[5];
  p.tmv   = (const float*)d_in[6];
  p.tmr   = (const float*)d_in[7];
  p.tf    = (const float*)d_in[8];
  p.td    = (const float*)d_in[9];
  p.kw    = (const float*)d_in[10];
  p.vw    = (const float*)d_in[11];
  p.rw    = (const float*)d_in[12];
  p.ow    = (const float*)d_in[13];
  p.ln2_w = (const float*)d_in[14];
  p.ln2_b = (const float*)d_in[15];
  p.ftmk  = (const float*)d_in[16];
  p.ftmr  = (const float*)d_in[17];
  p.fkw   = (const float*)d_in[18];
  p.fvw   = (const float*)d_in[19];
  p.frw   = (const float*)d_in[20];
  p.lnow  = (const float*)d_in[21];
  p.lnob  = (const float*)d_in[22];
  p.headw = (const float*)d_in[23];
  if (in_sizes[24] == 1) {
    p.tok = (const int*)d_in[24];
    p.st  = (const float*)d_in[25];
  } else {
    p.st  = (const float*)d_in[24];
    p.tok = (const int*)d_in[25];
  }
  p.out   = (float*)d_out;
  p.ws    = (float*)d_ws;

  // zero the barrier counter region deterministically every call (graph node)
  hipMemsetAsync(d_ws, 0, 256, stream);

  void* args[] = { &p };
  hipLaunchCooperativeKernel((const void*)rwkv_kernel, dim3(NB), dim3(NT),
                             args, 0, stream);
}

// Round 4
// 872.372 us; speedup vs baseline: 3.5942x; 2.0399x over previous
//
#include <hip/hip_runtime.h>

#define E 1024
#define H 4096
#define NLAYER 24
#define V 50277
#define NB 256
#define NT 1024
#define NWAVE ((NB * NT) / 64)   // 4096 waves
#define LN_EPS 1e-5f

struct Params {
  const float* emb;   const float* ln0_w; const float* ln0_b;
  const float* ln1_w; const float* ln1_b;
  const float* tmk;   const float* tmv;   const float* tmr;
  const float* tf;    const float* td;
  const float* kw;    const float* vw;    const float* rw;  const float* ow;
  const float* ln2_w; const float* ln2_b;
  const float* ftmk;  const float* ftmr;
  const float* fkw;   const float* fvw;   const float* frw;
  const float* lnow;  const float* lnob;  const float* headw;
  const float* st;    const int* tok;
  float* out; float* ws;
};

// ---- agent-scope (device-coherent, cache-bypassing) load/store helpers ----
__device__ __forceinline__ void stg(float* p, float v) {
  __hip_atomic_store(p, v, __ATOMIC_RELAXED, __HIP_MEMORY_SCOPE_AGENT);
}
__device__ __forceinline__ float ldg1(const float* p) {
  return __hip_atomic_load(p, __ATOMIC_RELAXED, __HIP_MEMORY_SCOPE_AGENT);
}

// ---- two-level relaxed grid barrier ----
// All data handoff is via relaxed agent-scope atomics (sc1 -> MALL), so no
// L2 writeback/invalidate fences are needed; only vmcnt drain before arrival.
// subs: 32 counters spaced 256B; super: one counter. Zeroed by hipMemsetAsync
// before every launch. Monotonic generation targets (no reset mid-kernel).
__device__ __forceinline__ void gbar(unsigned* subs, unsigned* super,
                                     unsigned gen, int bid) {
  // every wave: ensure its sc1 data stores are acked at the coherence point
  asm volatile("s_waitcnt vmcnt(0) lgkmcnt(0)" ::: "memory");
  __syncthreads();
  if (threadIdx.x == 0) {
    unsigned* sc = subs + (bid & 31) * 64;   // 256B apart
    unsigned old = __hip_atomic_fetch_add(sc, 1u, __ATOMIC_RELAXED,
                                          __HIP_MEMORY_SCOPE_AGENT);
    if (old + 1 == gen * 8u) {               // last of this group's 8 blocks
      __hip_atomic_fetch_add(super, 1u, __ATOMIC_RELAXED,
                             __HIP_MEMORY_SCOPE_AGENT);
    }
    while (__hip_atomic_load(super, __ATOMIC_RELAXED,
                             __HIP_MEMORY_SCOPE_AGENT) < gen * 32u)
      __builtin_amdgcn_s_sleep(2);
  }
  __syncthreads();
}

__device__ __forceinline__ float warp_sum(float v) {
#pragma unroll
  for (int off = 32; off; off >>= 1) v += __shfl_down(v, off);
  return v;
}

// full-block (1024-thread) sum; red is 16-entry LDS scratch
__device__ float block_sum(float v, float* red) {
  v = warp_sum(v);
  const int wid = threadIdx.x >> 6, lane = threadIdx.x & 63;
  if (lane == 0) red[wid] = v;
  __syncthreads();
  float s = (threadIdx.x < 16) ? red[threadIdx.x] : 0.f;
  if (wid == 0) {
#pragma unroll
    for (int off = 8; off; off >>= 1) s += __shfl_down(s, off);
    if (lane == 0) red[0] = s;
  }
  __syncthreads();
  float r = red[0];
  __syncthreads();
  return r;
}

// K=1024 dot: wave-wide, lane reads 4x float4; result valid in lane 0
__device__ __forceinline__ float dot1024(const float* __restrict__ Wrow,
                                         const float* vec, int lane) {
  const float4* W4 = (const float4*)Wrow;
  const float4* v4 = (const float4*)vec;
  float acc = 0.f;
#pragma unroll
  for (int p = 0; p < 4; ++p) {
    float4 w = W4[lane + p * 64];
    float4 x = v4[lane + p * 64];
    acc += w.x * x.x + w.y * x.y + w.z * x.z + w.w * x.w;
  }
  return warp_sum(acc);
}

__global__ __launch_bounds__(NT, 1) void rwkv_kernel(Params p) {
  const int tid = threadIdx.x, bid = blockIdx.x;
  const int lane = tid & 63, wid = tid >> 6;
  const int gw = bid * (NT / 64) + wid;   // global wave id, 0..4095

  __shared__ __align__(16) float s_x[E];
  __shared__ __align__(16) float s_xk[E];
  __shared__ __align__(16) float s_xv[E];
  __shared__ __align__(16) float s_xr[E];
  __shared__ __align__(16) float s_wkv[E];
  __shared__ __align__(16) float s_sx[E];
  __shared__ __align__(16) float s_fxk[E];
  __shared__ __align__(16) float s_fxr[E];
  __shared__ __align__(16) float s_fk[H];
  __shared__ float s_red[16];
  __shared__ float s_part[16];

  // ws layout: [0..4096) floats = control; data after
  unsigned* ctl = (unsigned*)p.ws;
  unsigned* subs  = ctl;            // 32 counters, stride 64 uints (256B)
  unsigned* super = ctl + 2048;     // separate line
  float* wsd  = p.ws + 4096;
  float* ws_x  = wsd;
  float* ws_k  = wsd + E;
  float* ws_v  = wsd + 2 * E;
  float* ws_r  = wsd + 3 * E;
  float* ws_sx = wsd + 4 * E;
  float* ws_fr = wsd + 5 * E;
  float* ws_fk = wsd + 6 * E;          // H floats

  unsigned gen = 0;

  float* out_st = p.out + V;

  const int token = p.tok[0];

  // x = LN0(emb[token]) -- redundant per block, lives in s_x
  {
    float v = p.emb[(size_t)token * E + tid];
    float m = block_sum(v, s_red) * (1.f / E);
    float d = v - m;
    float var = block_sum(d * d, s_red) * (1.f / E);
    s_x[tid] = d / sqrtf(var + LN_EPS) * p.ln0_w[tid] + p.ln0_b[tid];
  }
  __syncthreads();

  for (int l = 0; l < NLAYER; ++l) {
    const float* stl = p.st + (size_t)5 * l * E;   // [ffn_x, att_x, aa, bb, pp]
    float* ostl = out_st + (size_t)5 * l * E;

    // ---------------- Phase A: LN1, mixing, k/v/r matvecs ----------------
    {
      float xv_ = s_x[tid];
      float m = block_sum(xv_, s_red) * (1.f / E);
      float d = xv_ - m;
      float var = block_sum(d * d, s_red) * (1.f / E);
      float xn = d / sqrtf(var + LN_EPS) * p.ln1_w[l * E + tid] + p.ln1_b[l * E + tid];
      float ax = stl[1 * E + tid];
      float tk = p.tmk[l * E + tid], tv = p.tmv[l * E + tid], tr = p.tmr[l * E + tid];
      s_xk[tid] = xn * tk + ax * (1.f - tk);
      s_xv[tid] = xn * tv + ax * (1.f - tv);
      s_xr[tid] = xn * tr + ax * (1.f - tr);
      if (bid == 0) ostl[1 * E + tid] = xn;       // new att_x
    }
    __syncthreads();
    {
      int row = gw;                                // 3072 rows over 4096 waves
      if (row < 3 * E) {
        int mat = row >> 10, rm = row & (E - 1);
        const float* W; const float* vec;
        if (mat == 0)      { W = p.kw + (size_t)l * E * E; vec = s_xk; }
        else if (mat == 1) { W = p.vw + (size_t)l * E * E; vec = s_xv; }
        else               { W = p.rw + (size_t)l * E * E; vec = s_xr; }
        float dres = dot1024(W + (size_t)rm * E, vec, lane);
        if (lane == 0) {
          if (mat == 0)      stg(&ws_k[rm], dres);
          else if (mat == 1) stg(&ws_v[rm], dres);
          else               stg(&ws_r[rm], 1.f / (1.f + expf(-dres)));
        }
      }
    }
    gbar(subs, super, ++gen, bid);

    // ---------------- Phase B: WKV elementwise + ow matvec ----------------
    {
      float kk = ldg1(&ws_k[tid]), vv = ldg1(&ws_v[tid]), rr = ldg1(&ws_r[tid]);
      float ppv = stl[4 * E + tid], aav = stl[2 * E + tid], bbv = stl[3 * E + tid];
      float tfv = p.tf[l * E + tid], tdv = p.td[l * E + tid];
      float wwv = tfv + kk;
      float pm = fmaxf(ppv, wwv);
      float e1 = expf(ppv - pm), e2 = expf(wwv - pm);
      float a = e1 * aav + e2 * vv, b = e1 * bbv + e2;
      s_wkv[tid] = rr * a / b;
      float ww2 = ppv + tdv;
      float p2 = fmaxf(ww2, kk);
      float f1 = expf(ww2 - p2), f2 = expf(kk - p2);
      if (bid == 0) {
        ostl[2 * E + tid] = f1 * aav + f2 * vv;    // naa
        ostl[3 * E + tid] = f1 * bbv + f2;         // nbb
        ostl[4 * E + tid] = p2;                    // npp
      }
    }
    __syncthreads();
    {
      // 4 rows/block, 4 waves/row, K-chunks of 256
      int rloc = wid >> 2, kc = wid & 3;
      int row = bid * 4 + rloc;
      const float* Wrow = p.ow + (size_t)l * E * E + (size_t)row * E + kc * 256;
      const float4* W4 = (const float4*)Wrow;
      const float4* v4 = (const float4*)(s_wkv + kc * 256);
      float4 w = W4[lane]; float4 x = v4[lane];
      float acc = warp_sum(w.x * x.x + w.y * x.y + w.z * x.z + w.w * x.w);
      if (lane == 0) s_part[wid] = acc;
      __syncthreads();
      if (tid < 4) {
        int r2 = bid * 4 + tid;
        float dsum = s_part[tid * 4] + s_part[tid * 4 + 1] +
                     s_part[tid * 4 + 2] + s_part[tid * 4 + 3];
        stg(&ws_sx[r2], s_x[r2] + dsum);
      }
    }
    gbar(subs, super, ++gen, bid);

    // ---------------- Phase C: LN2, mixing, ffn_kw/frw matvecs ----------------
    {
      float sxv = ldg1(&ws_sx[tid]);
      s_sx[tid] = sxv;
      float m = block_sum(sxv, s_red) * (1.f / E);
      float d = sxv - m;
      float var = block_sum(d * d, s_red) * (1.f / E);
      float xn2 = d / sqrtf(var + LN_EPS) * p.ln2_w[l * E + tid] + p.ln2_b[l * E + tid];
      float fx = stl[0 * E + tid];
      float ftk = p.ftmk[l * E + tid], ftr = p.ftmr[l * E + tid];
      s_fxk[tid] = xn2 * ftk + fx * (1.f - ftk);
      s_fxr[tid] = xn2 * ftr + fx * (1.f - ftr);
      if (bid == 0) ostl[0 * E + tid] = xn2;       // new ffn_x
    }
    __syncthreads();
    {
      for (int row = gw; row < H + E; row += NWAVE) {   // 5120 rows
        if (row < H) {
          const float* Wr = p.fkw + (size_t)l * H * E + (size_t)row * E;
          float dres = dot1024(Wr, s_fxk, lane);
          if (lane == 0) { float t = fmaxf(dres, 0.f); stg(&ws_fk[row], t * t); }
        } else {
          int rr2 = row - H;
          const float* Wr = p.frw + (size_t)l * E * E + (size_t)rr2 * E;
          float dres = dot1024(Wr, s_fxr, lane);
          if (lane == 0) stg(&ws_fr[rr2], 1.f / (1.f + expf(-dres)));
        }
      }
    }
    gbar(subs, super, ++gen, bid);

    // ---------------- Phase D: fvw matvec (K=4096), residual ----------------
    {
#pragma unroll
      for (int i = 0; i < 4; ++i) s_fk[tid + i * NT] = ldg1(&ws_fk[tid + i * NT]);
      __syncthreads();
      int rloc = wid >> 2, kc = wid & 3;               // kc: 1024-wide chunk
      int row = bid * 4 + rloc;
      const float* Wrow = p.fvw + (size_t)l * E * H + (size_t)row * H + kc * 1024;
      const float4* W4 = (const float4*)Wrow;
      const float4* v4 = (const float4*)(s_fk + kc * 1024);
      float acc = 0.f;
#pragma unroll
      for (int pc = 0; pc < 4; ++pc) {
        float4 w = W4[lane + pc * 64];
        float4 x = v4[lane + pc * 64];
        acc += w.x * x.x + w.y * x.y + w.z * x.z + w.w * x.w;
      }
      acc = warp_sum(acc);
      if (lane == 0) s_part[wid] = acc;
      __syncthreads();
      if (tid < 4) {
        int r2 = bid * 4 + tid;
        float dsum = s_part[tid * 4] + s_part[tid * 4 + 1] +
                     s_part[tid * 4 + 2] + s_part[tid * 4 + 3];
        stg(&ws_x[r2], s_sx[r2] + ldg1(&ws_fr[r2]) * dsum);
      }
    }
    gbar(subs, super, ++gen, bid);

    // reload x for next layer
    s_x[tid] = ldg1(&ws_x[tid]);
    __syncthreads();
  }

  // ---------------- Head: LN_out + V x E matvec ----------------
  {
    float xv_ = s_x[tid];
    float m = block_sum(xv_, s_red) * (1.f / E);
    float d = xv_ - m;
    float var = block_sum(d * d, s_red) * (1.f / E);
    s_xk[tid] = d / sqrtf(var + LN_EPS) * p.lnow[tid] + p.lnob[tid];
  }
  __syncthreads();
  for (int row = gw; row < V; row += NWAVE) {
    const float* Wr = p.headw + (size_t)row * E;
    float dres = dot1024(Wr, s_xk, lane);
    if (lane == 0) p.out[row] = dres;
  }
}

extern "C" void kernel_launch(void* const* d_in, const int* in_sizes, int n_in,
                              void* d_out, int out_size, void* d_ws, size_t ws_size,
                              hipStream_t stream) {
  Params p;
  p.emb   = (const float*)d_in[0];
  p.ln0_w = (const float*)d_in[1];
  p.ln0_b = (const float*)d_in[2];
  p.ln1_w = (const float*)d_in[3];
  p.ln1_b = (const float*)d_in[4];
  p.tmk   = (const float*)d_in[5];
  p.tmv   = (const float*)d_in[6];
  p.tmr   = (const float*)d_in[7];
  p.tf    = (const float*)d_in[8];
  p.td    = (const float*)d_in[9];
  p.kw    = (const float*)d_in[10];
  p.vw    = (const float*)d_in[11];
  p.rw    = (const float*)d_in[12];
  p.ow    = (const float*)d_in[13];
  p.ln2_w = (const float*)d_in[14];
  p.ln2_b = (const float*)d_in[15];
  p.ftmk  = (const float*)d_in[16];
  p.ftmr  = (const float*)d_in[17];
  p.fkw   = (const float*)d_in[18];
  p.fvw   = (const float*)d_in[19];
  p.frw   = (const float*)d_in[20];
  p.lnow  = (const float*)d_in[21];
  p.lnob  = (const float*)d_in[22];
  p.headw = (const float*)d_in[23];
  if (in_sizes[24] == 1) {
    p.tok = (const int*)d_in[24];
    p.st  = (const float*)d_in[25];
  } else {
    p.st  = (const float*)d_in[24];
    p.tok = (const int*)d_in[25];
  }
  p.out   = (float*)d_out;
  p.ws    = (float*)d_ws;

  // zero the barrier counter region deterministically every call (graph node)
  hipMemsetAsync(d_ws, 0, 16384, stream);

  void* args[] = { &p };
  hipLaunchCooperativeKernel((const void*)rwkv_kernel, dim3(NB), dim3(NT),
                             args, 0, stream);
}